// Round 17
// baseline (209.839 us; speedup 1.0000x reference)
//
#include <hip/hip_runtime.h>
#include <hip/hip_bf16.h>
#include <stdint.h>

typedef short sh4 __attribute__((ext_vector_type(4)));
typedef short sh8 __attribute__((ext_vector_type(8)));
typedef float fl4 __attribute__((ext_vector_type(4)));
typedef float f32x4 __attribute__((ext_vector_type(4)));
typedef float f32x16 __attribute__((ext_vector_type(16)));
typedef uint32_t u32x4 __attribute__((ext_vector_type(4)));

static __device__ __forceinline__ short f2bf(float f) {
  union { float f; uint32_t u; } v;
  v.f = f;
  uint32_t r = v.u + 0x7fffu + ((v.u >> 16) & 1u);
  return (short)(r >> 16);
}

static __device__ __forceinline__ uint32_t cvt_pk_bf16(float a, float b) {
  uint32_t r;
  asm("v_cvt_pk_bf16_f32 %0, %1, %2" : "=v"(r) : "v"(a), "v"(b));
  return r;
}

static __device__ __forceinline__ void pl32swap(uint32_t& a, uint32_t& b) {
  asm volatile("v_permlane32_swap_b32 %0, %1" : "+v"(a), "+v"(b));
}

static __device__ __forceinline__ void gload_lds16(const void* g, void* l) {
  __builtin_amdgcn_global_load_lds((const __attribute__((address_space(1))) void*)g,
                                   (__attribute__((address_space(3))) void*)l, 16, 0, 0);
}

// ---------- weight transpose + convert (z<4): T[n][k] = bf16(W[k][n]); z==4: x -> bf16 ----------
__global__ __launch_bounds__(256) void k_wt(const float* __restrict__ Wq, const float* __restrict__ Wk,
                                            const float* __restrict__ Wv, const float* __restrict__ Wo,
                                            short* __restrict__ Tq, short* __restrict__ Tk,
                                            short* __restrict__ Tv, short* __restrict__ To,
                                            const float* __restrict__ x, short* __restrict__ xbf) {
  if (blockIdx.z == 4) {
    int tid = threadIdx.y * 32 + threadIdx.x;
    size_t base = ((size_t)blockIdx.y * 32 + blockIdx.x) * 8192;
#pragma unroll
    for (int i = 0; i < 8; i++) {
      size_t idx = base + (size_t)i * 1024 + tid * 4;
      fl4 v = *(const fl4*)&x[idx];
      sh4 r;
#pragma unroll
      for (int j = 0; j < 4; j++) r[j] = f2bf(v[j]);
      *(sh4*)&xbf[idx] = r;
    }
    return;
  }
  const float* W = blockIdx.z == 0 ? Wq : blockIdx.z == 1 ? Wk : blockIdx.z == 2 ? Wv : Wo;
  short* T = blockIdx.z == 0 ? Tq : blockIdx.z == 1 ? Tk : blockIdx.z == 2 ? Tv : To;
  __shared__ float tile[32][33];
  int n0 = blockIdx.x * 32, k0 = blockIdx.y * 32;
  int tx = threadIdx.x, ty = threadIdx.y;
#pragma unroll
  for (int p = 0; p < 4; p++) tile[ty + 8 * p][tx] = W[(size_t)(k0 + ty + 8 * p) * 1024 + n0 + tx];
  __syncthreads();
#pragma unroll
  for (int p = 0; p < 4; p++) T[(size_t)(n0 + ty + 8 * p) * 1024 + k0 + tx] = f2bf(tile[tx][ty + 8 * p]);
}

// ======== counted-vmcnt 3-buffer pipeline; VM = per-wave loads per tile (string literal) ========
#define PIPE_LOOP(STAGE_BODY, COMPUTE_BODY, VM)                          \
  STAGE_BODY(0, 0);                                                      \
  STAGE_BODY(1, 1);                                                      \
  {                                                                      \
    int bufc = 0, bufs = 2;                                              \
    for (int it = 0; it < 32; it++) {                                    \
      if (it < 31)                                                       \
        asm volatile("s_waitcnt vmcnt(" VM ")" ::: "memory");            \
      else                                                               \
        asm volatile("s_waitcnt vmcnt(0)" ::: "memory");                 \
      __builtin_amdgcn_s_barrier();                                      \
      if (it + 2 < 32) { STAGE_BODY(it + 2, bufs); }                     \
      __builtin_amdgcn_sched_barrier(0);                                 \
      { int buf = bufc; COMPUTE_BODY }                                   \
      bufc = bufc == 2 ? 0 : bufc + 1;                                   \
      bufs = bufs == 2 ? 0 : bufs + 1;                                   \
      asm volatile("" ::: "memory");                                     \
    }                                                                    \
  }

// ---------- fused Q/K/V projection GEMM: 768 blocks, 512 threads, 256x128 tiles ----------
// bid < 512: QK role (swapped frags, N=2048 over WT2). bid >= 512: V role (plain frags,
// N=1024 over WTv, output [B,H,Dh,S]). Roles uniform per block; V blocks backfill slots
// freed by finishing QK blocks (one dispatch, no serial boundary).
__global__ __launch_bounds__(512, 4) void k_qkv(const short* __restrict__ A, const short* __restrict__ WT2,
                                                const short* __restrict__ WTv,
                                                const float* __restrict__ bq, const float* __restrict__ bk,
                                                const float* __restrict__ bv,
                                                short* __restrict__ Qo, short* __restrict__ Ko,
                                                short* __restrict__ Vo, float qscale) {
  __shared__ __align__(16) short As[3][256 * 32];  // 48KB
  __shared__ __align__(16) short Bs[3][128 * 32];  // 24KB
  const int bid = blockIdx.x;
  const int t = threadIdx.x;
  const int lane = t & 63, w = t >> 6;
  const int wr = w >> 1, wc = w & 1;
  const int l15 = lane & 15, g = lane >> 4;
  f32x4 acc[4][4];
#pragma unroll
  for (int mi = 0; mi < 4; mi++)
#pragma unroll
    for (int ni = 0; ni < 4; ni++) acc[mi][ni] = (f32x4){0.f, 0.f, 0.f, 0.f};

  if (bid < 512) {
    // ---------------- QK role ----------------
    const int xcd = bid & 7, j = bid >> 3;
    const int m0 = (j >> 1) * 256, n0 = (xcd * 2 + (j & 1)) * 128;
    const int sec = n0 >> 10;  // 0=Q 1=K
    const float* bias = sec == 0 ? bq : bk;
    short* Out = sec == 0 ? Qo : Ko;
    const float scale = sec == 0 ? qscale : 1.f;

#define QK_STAGE(kt, buf)                                                                     \
  {                                                                                           \
    int r0 = w * 32;                                                                          \
    _Pragma("unroll") for (int i = 0; i < 2; i++) {                                           \
      int row = r0 + i * 16 + (lane >> 2);                                                    \
      gload_lds16(&A[(size_t)(m0 + row) * 1024 + (kt) * 32 + (lane & 3) * 8],                 \
                  &As[buf][(r0 + i * 16) * 32]);                                              \
    }                                                                                         \
    int brow = w * 16 + (lane >> 2);                                                          \
    gload_lds16(&WT2[(size_t)(n0 + brow) * 1024 + (kt) * 32 + (lane & 3) * 8],                \
                &Bs[buf][(w * 16) * 32]);                                                     \
  }

#define QK_COMPUTE                                                                            \
  sh8 a[4], b[4];                                                                             \
  _Pragma("unroll") for (int i = 0; i < 4; i++)                                               \
      a[i] = *(sh8*)&As[buf][(wr * 64 + i * 16 + l15) * 32 + g * 8];                          \
  _Pragma("unroll") for (int i = 0; i < 4; i++)                                               \
      b[i] = *(sh8*)&Bs[buf][(wc * 64 + i * 16 + l15) * 32 + g * 8];                          \
  _Pragma("unroll") for (int mi = 0; mi < 4; mi++)                                            \
      _Pragma("unroll") for (int ni = 0; ni < 4; ni++)                                        \
          acc[mi][ni] = __builtin_amdgcn_mfma_f32_16x16x32_bf16(b[ni], a[mi], acc[mi][ni], 0, 0, 0);

    PIPE_LOOP(QK_STAGE, QK_COMPUTE, "3")

#pragma unroll
    for (int ni = 0; ni < 4; ni++) {
      int nbase = n0 + wc * 64 + ni * 16 + g * 4;
      int nn0 = nbase & 1023;
      fl4 bv4 = *(const fl4*)&bias[nn0];
      int h = nn0 >> 6, dh0 = nn0 & 63;
#pragma unroll
      for (int mi = 0; mi < 4; mi++) {
        int m = m0 + wr * 64 + mi * 16 + l15;
        int bb = m >> 11, s = m & 2047;
        uint2 dd;
        dd.x = cvt_pk_bf16((acc[mi][ni][0] + bv4[0]) * scale, (acc[mi][ni][1] + bv4[1]) * scale);
        dd.y = cvt_pk_bf16((acc[mi][ni][2] + bv4[2]) * scale, (acc[mi][ni][3] + bv4[3]) * scale);
        *(uint2*)&Out[(((size_t)bb * 16 + h) * 2048 + s) * 64 + dh0] = dd;
      }
    }
  } else {
    // ---------------- V role ----------------
    const int vb = bid - 512;
    const int xcd = vb & 7, jj = vb >> 3;     // jj in [0,32)
    const int m0 = jj * 256, n0 = xcd * 128;  // N=1024, xcd owns one n-tile

#define V_STAGE(kt, buf)                                                                      \
  {                                                                                           \
    int r0 = w * 32;                                                                          \
    _Pragma("unroll") for (int i = 0; i < 2; i++) {                                           \
      int row = r0 + i * 16 + (lane >> 2);                                                    \
      gload_lds16(&A[(size_t)(m0 + row) * 1024 + (kt) * 32 + (lane & 3) * 8],                 \
                  &As[buf][(r0 + i * 16) * 32]);                                              \
    }                                                                                         \
    int brow = w * 16 + (lane >> 2);                                                          \
    gload_lds16(&WTv[(size_t)(n0 + brow) * 1024 + (kt) * 32 + (lane & 3) * 8],                \
                &Bs[buf][(w * 16) * 32]);                                                     \
  }

#define V_COMPUTE                                                                             \
  sh8 a[4], b[4];                                                                             \
  _Pragma("unroll") for (int i = 0; i < 4; i++)                                               \
      a[i] = *(sh8*)&As[buf][(wr * 64 + i * 16 + l15) * 32 + g * 8];                          \
  _Pragma("unroll") for (int i = 0; i < 4; i++)                                               \
      b[i] = *(sh8*)&Bs[buf][(wc * 64 + i * 16 + l15) * 32 + g * 8];                          \
  _Pragma("unroll") for (int mi = 0; mi < 4; mi++)                                            \
      _Pragma("unroll") for (int ni = 0; ni < 4; ni++)                                        \
          acc[mi][ni] = __builtin_amdgcn_mfma_f32_16x16x32_bf16(a[mi], b[ni], acc[mi][ni], 0, 0, 0);

    PIPE_LOOP(V_STAGE, V_COMPUTE, "3")

#pragma unroll
    for (int ni = 0; ni < 4; ni++) {
      int col = n0 + wc * 64 + ni * 16 + l15;
      float bvv = bv[col];
      int h = col >> 6, dh = col & 63;
#pragma unroll
      for (int mi = 0; mi < 4; mi++) {
        int mr = m0 + wr * 64 + mi * 16 + g * 4;
        int bb = mr >> 11, s = mr & 2047;
        uint2 dd;
        dd.x = cvt_pk_bf16(acc[mi][ni][0] + bvv, acc[mi][ni][1] + bvv);
        dd.y = cvt_pk_bf16(acc[mi][ni][2] + bvv, acc[mi][ni][3] + bvv);
        *(uint2*)&Vo[(((size_t)bb * 16 + h) * 64 + dh) * 2048 + s] = dd;
      }
    }
  }
}

// ---------- output projection GEMM + bias + residual ----------
__global__ __launch_bounds__(256) void k_oproj(const short* __restrict__ A, const short* __restrict__ BT,
                                               const float* __restrict__ bias, const float* __restrict__ X,
                                               float* __restrict__ Out) {
  __shared__ __align__(16) short As[3][128 * 32];
  __shared__ __align__(16) short Bs[3][128 * 32];
  const int xcd = blockIdx.x & 7, j = blockIdx.x >> 3;
  const int m0 = (xcd + 8 * (j & 7)) * 128, n0 = (j >> 3) * 128;
  const int t = threadIdx.x;
  const int lane = t & 63, w = t >> 6;
  const int wr = w >> 1, wc = w & 1;
  const int l15 = lane & 15, g = lane >> 4;
  f32x4 acc[4][4];
#pragma unroll
  for (int mi = 0; mi < 4; mi++)
#pragma unroll
    for (int ni = 0; ni < 4; ni++) acc[mi][ni] = (f32x4){0.f, 0.f, 0.f, 0.f};

#define O_STAGE(kt, buf)                                                                      \
  {                                                                                           \
    int r0 = w * 32;                                                                          \
    _Pragma("unroll") for (int i = 0; i < 2; i++) {                                           \
      int row = r0 + i * 16 + (lane >> 2);                                                    \
      gload_lds16(&A[(size_t)(m0 + row) * 1024 + (kt) * 32 + (lane & 3) * 8],                 \
                  &As[buf][(r0 + i * 16) * 32]);                                              \
      gload_lds16(&BT[(size_t)(n0 + row) * 1024 + (kt) * 32 + (lane & 3) * 8],                \
                  &Bs[buf][(r0 + i * 16) * 32]);                                              \
    }                                                                                         \
  }

#define O_COMPUTE                                                                             \
  sh8 a[4], b[4];                                                                             \
  _Pragma("unroll") for (int i = 0; i < 4; i++)                                               \
      a[i] = *(sh8*)&As[buf][(wr * 64 + i * 16 + l15) * 32 + g * 8];                          \
  _Pragma("unroll") for (int i = 0; i < 4; i++)                                               \
      b[i] = *(sh8*)&Bs[buf][(wc * 64 + i * 16 + l15) * 32 + g * 8];                          \
  _Pragma("unroll") for (int mi = 0; mi < 4; mi++)                                            \
      _Pragma("unroll") for (int ni = 0; ni < 4; ni++)                                        \
          acc[mi][ni] = __builtin_amdgcn_mfma_f32_16x16x32_bf16(b[ni], a[mi], acc[mi][ni], 0, 0, 0);

  PIPE_LOOP(O_STAGE, O_COMPUTE, "4")

#pragma unroll
  for (int ni = 0; ni < 4; ni++) {
    int nbase = n0 + wc * 64 + ni * 16 + g * 4;
    fl4 bv4 = *(const fl4*)&bias[nbase];
#pragma unroll
    for (int mi = 0; mi < 4; mi++) {
      int m = m0 + wr * 64 + mi * 16 + l15;
      fl4 xv = *(const fl4*)&X[(size_t)m * 1024 + nbase];
      fl4 r;
#pragma unroll
      for (int e = 0; e < 4; e++) r[e] = acc[mi][ni][e] + bv4[e] + xv[e];
      *(fl4*)&Out[(size_t)m * 1024 + nbase] = r;
    }
  }
}

// ---------- flash attention v9 (best known): cross-tile pipelined, frag-order LDS ----------
__global__ __launch_bounds__(512, 4) void k_attn(const short* __restrict__ Q, const short* __restrict__ K,
                                                 const short* __restrict__ Vt, short* __restrict__ CTX) {
  const int nid = (blockIdx.x & 7) * 64 + (blockIdx.x >> 3);
  const int qbi = nid & 7, h = (nid >> 3) & 15, b = nid >> 7;
  const int q0 = qbi * 256;
  const size_t ho = (((size_t)b * 16 + h) * 2048) * 64;
  const short* Qh = Q + ho;
  const short* Kh = K + ho;
  const short* Vh = Vt + ho;
  __shared__ __align__(16) short Ks[3][8 * 512];  // 24KB
  __shared__ __align__(16) short Vs[4][8 * 512];  // 32KB
  const int t = threadIdx.x, lane = t & 63, w = t >> 6;  // w in [0,8)
  const int l31 = lane & 31, hi = lane >> 5;

  sh8 qreg[4];
#pragma unroll
  for (int ks = 0; ks < 4; ks++)
    qreg[ks] = *(const sh8*)&Qh[(size_t)(q0 + w * 32 + l31) * 64 + ks * 16 + hi * 8];

  f32x16 zinit;
#pragma unroll
  for (int r = 0; r < 16; r++) zinit[r] = 0.f;

  f32x16 oc0 = zinit, oc1 = zinit;
  float l_s = 0.f;
  u32x4 pwp[4];  // packed P of previous tile

  auto stageK = [&](int kt, int buf) {
    gload_lds16(&Kh[(size_t)(kt * 64 + (w >> 2) * 32 + l31) * 64 + (w & 3) * 16 + hi * 8],
                (char*)&Ks[buf][0] + w * 1024);
  };
  auto stageV = [&](int kt, int buf) {
    gload_lds16(&Vh[(size_t)((w >> 2) * 32 + l31) * 2048 + kt * 64 + (w & 3) * 16 + hi * 8],
                (char*)&Vs[buf][0] + w * 1024);
  };

  stageK(0, 0); stageV(0, 0);
  stageK(1, 1); stageV(1, 1);

  for (int kt = 0; kt < 32; kt++) {
    if (kt < 31)
      asm volatile("s_waitcnt vmcnt(2)" ::: "memory");
    else
      asm volatile("s_waitcnt vmcnt(0)" ::: "memory");
    __builtin_amdgcn_s_barrier();
    if (kt + 2 < 32) { stageK(kt + 2, (kt + 2) % 3); stageV(kt + 2, (kt + 2) & 3); }
    __builtin_amdgcn_sched_barrier(0);
    const int kbuf = kt % 3;

    // ---- QK(t): issue first so results cook while PV(t-1) runs ----
    f32x16 s0, s1;
    __builtin_amdgcn_s_setprio(1);
#pragma unroll
    for (int ks = 0; ks < 4; ks++) {
      sh8 ak0 = *(sh8*)((char*)&Ks[kbuf][0] + ks * 1024 + lane * 16);
      sh8 ak1 = *(sh8*)((char*)&Ks[kbuf][0] + (4 + ks) * 1024 + lane * 16);
      if (ks == 0) {
        s0 = __builtin_amdgcn_mfma_f32_32x32x16_bf16(ak0, qreg[0], zinit, 0, 0, 0);
        s1 = __builtin_amdgcn_mfma_f32_32x32x16_bf16(ak1, qreg[0], zinit, 0, 0, 0);
      } else {
        s0 = __builtin_amdgcn_mfma_f32_32x32x16_bf16(ak0, qreg[ks], s0, 0, 0, 0);
        s1 = __builtin_amdgcn_mfma_f32_32x32x16_bf16(ak1, qreg[ks], s1, 0, 0, 0);
      }
    }

    // ---- PV(t-1): independent MFMA work filling the QK latency gap ----
    if (kt > 0) {
      const int vb = (kt - 1) & 3;
#pragma unroll
      for (int ks = 0; ks < 4; ks++) {
        sh8 pb = __builtin_bit_cast(sh8, pwp[ks]);
        sh8 av0 = *(sh8*)((char*)&Vs[vb][0] + ks * 1024 + lane * 16);
        sh8 av1 = *(sh8*)((char*)&Vs[vb][0] + (4 + ks) * 1024 + lane * 16);
        oc0 = __builtin_amdgcn_mfma_f32_32x32x16_bf16(av0, pb, oc0, 0, 0, 0);
        oc1 = __builtin_amdgcn_mfma_f32_32x32x16_bf16(av1, pb, oc1, 0, 0, 0);
      }
    }
    __builtin_amdgcn_s_setprio(0);

    // ---- softmax numerator p = exp2(s); accumulate denominator ----
    float ps = 0.f;
#pragma unroll
    for (int r = 0; r < 16; r++) { s0[r] = __builtin_amdgcn_exp2f(s0[r]); ps += s0[r]; }
#pragma unroll
    for (int r = 0; r < 16; r++) { s1[r] = __builtin_amdgcn_exp2f(s1[r]); ps += s1[r]; }
    l_s += ps;

    // ---- pack P -> pwp (cvt_pk + permlane32_swap), used by NEXT iteration's PV ----
    {
      uint32_t a0 = cvt_pk_bf16(s0[0], s0[1]), a1 = cvt_pk_bf16(s0[2], s0[3]);
      uint32_t b0 = cvt_pk_bf16(s0[4], s0[5]), b1 = cvt_pk_bf16(s0[6], s0[7]);
      uint32_t c0 = cvt_pk_bf16(s0[8], s0[9]), c1 = cvt_pk_bf16(s0[10], s0[11]);
      uint32_t d0 = cvt_pk_bf16(s0[12], s0[13]), d1 = cvt_pk_bf16(s0[14], s0[15]);
      pl32swap(a0, b0); pl32swap(a1, b1); pl32swap(c0, d0); pl32swap(c1, d1);
      pwp[0] = (u32x4){a0, a1, b0, b1};
      pwp[1] = (u32x4){c0, c1, d0, d1};
      a0 = cvt_pk_bf16(s1[0], s1[1]); a1 = cvt_pk_bf16(s1[2], s1[3]);
      b0 = cvt_pk_bf16(s1[4], s1[5]); b1 = cvt_pk_bf16(s1[6], s1[7]);
      c0 = cvt_pk_bf16(s1[8], s1[9]); c1 = cvt_pk_bf16(s1[10], s1[11]);
      d0 = cvt_pk_bf16(s1[12], s1[13]); d1 = cvt_pk_bf16(s1[14], s1[15]);
      pl32swap(a0, b0); pl32swap(a1, b1); pl32swap(c0, d0); pl32swap(c1, d1);
      pwp[2] = (u32x4){a0, a1, b0, b1};
      pwp[3] = (u32x4){c0, c1, d0, d1};
    }
    asm volatile("" ::: "memory");
  }

  // ---- tail: PV(31) ----
  {
    const int vb = 31 & 3;
    __builtin_amdgcn_s_setprio(1);
#pragma unroll
    for (int ks = 0; ks < 4; ks++) {
      sh8 pb = __builtin_bit_cast(sh8, pwp[ks]);
      sh8 av0 = *(sh8*)((char*)&Vs[vb][0] + ks * 1024 + lane * 16);
      sh8 av1 = *(sh8*)((char*)&Vs[vb][0] + (4 + ks) * 1024 + lane * 16);
      oc0 = __builtin_amdgcn_mfma_f32_32x32x16_bf16(av0, pb, oc0, 0, 0, 0);
      oc1 = __builtin_amdgcn_mfma_f32_32x32x16_bf16(av1, pb, oc1, 0, 0, 0);
    }
    __builtin_amdgcn_s_setprio(0);
  }

  l_s += __shfl_xor(l_s, 32);
  float li = 1.f / l_s;
  int s = q0 + w * 32 + l31;
  size_t obase = (((size_t)b * 2048 + s) * 16 + h) * 64;
#pragma unroll
  for (int rq = 0; rq < 4; rq++) {
    uint2 dd;
    dd.x = cvt_pk_bf16(oc0[4 * rq] * li, oc0[4 * rq + 1] * li);
    dd.y = cvt_pk_bf16(oc0[4 * rq + 2] * li, oc0[4 * rq + 3] * li);
    *(uint2*)&CTX[obase + rq * 8 + hi * 4] = dd;
    dd.x = cvt_pk_bf16(oc1[4 * rq] * li, oc1[4 * rq + 1] * li);
    dd.y = cvt_pk_bf16(oc1[4 * rq + 2] * li, oc1[4 * rq + 3] * li);
    *(uint2*)&CTX[obase + 32 + rq * 8 + hi * 4] = dd;
  }
}

// ---------- in-place LayerNorm over d_out rows ----------
__global__ __launch_bounds__(256) void k_ln(float* __restrict__ Out, const float* __restrict__ gamma,
                                            const float* __restrict__ beta) {
  int row = blockIdx.x * 4 + (threadIdx.x >> 6);
  int lane = threadIdx.x & 63;
  float* p = Out + (size_t)row * 1024;
  fl4 v[4];
  float s = 0.f, s2 = 0.f;
#pragma unroll
  for (int j = 0; j < 4; j++) {
    v[j] = *(fl4*)&p[lane * 4 + j * 256];
#pragma unroll
    for (int e = 0; e < 4; e++) { s += v[j][e]; s2 += v[j][e] * v[j][e]; }
  }
#pragma unroll
  for (int off = 1; off < 64; off <<= 1) {
    s += __shfl_xor(s, off);
    s2 += __shfl_xor(s2, off);
  }
  float mu = s * (1.f / 1024.f);
  float var = s2 * (1.f / 1024.f) - mu * mu;
  float inv = rsqrtf(var + 1e-5f);
#pragma unroll
  for (int j = 0; j < 4; j++) {
    fl4 r;
#pragma unroll
    for (int e = 0; e < 4; e++) {
      int c = lane * 4 + j * 256 + e;
      r[e] = (v[j][e] - mu) * inv * gamma[c] + beta[c];
    }
    *(fl4*)&p[lane * 4 + j * 256] = r;
  }
}

extern "C" void kernel_launch(void* const* d_in, const int* in_sizes, int n_in,
                              void* d_out, int out_size, void* d_ws, size_t ws_size,
                              hipStream_t stream) {
  (void)in_sizes; (void)n_in; (void)out_size; (void)ws_size;
  const float* x = (const float*)d_in[0];
  const float* Wq = (const float*)d_in[1];
  const float* bq = (const float*)d_in[2];
  const float* Wk = (const float*)d_in[3];
  const float* bk = (const float*)d_in[4];
  const float* Wv = (const float*)d_in[5];
  const float* bv = (const float*)d_in[6];
  const float* Wo = (const float*)d_in[7];
  const float* bo = (const float*)d_in[8];
  const float* gamma = (const float*)d_in[9];
  const float* beta = (const float*)d_in[10];
  float* out = (float*)d_out;
  char* ws = (char*)d_ws;
  short* xbf = (short*)(ws);
  short* wtq = (short*)(ws + (16ull << 20));  // wtq/wtk contiguous => WT2[2048][1024]
  short* wtk = (short*)(ws + (18ull << 20));
  short* wtv = (short*)(ws + (20ull << 20));
  short* wto = (short*)(ws + (22ull << 20));
  short* qb  = (short*)(ws + (24ull << 20));
  short* kbuf = (short*)(ws + (40ull << 20));
  short* vbuf = (short*)(ws + (56ull << 20));
  short* ctx = (short*)(ws + (72ull << 20));

  const float QSCALE = 0.125f * 1.44269504088896f;  // 1/sqrt(Dh) * log2(e)

  k_wt<<<dim3(32, 32, 5), dim3(32, 8), 0, stream>>>(Wq, Wk, Wv, Wo, wtq, wtk, wtv, wto, x, xbf);
  k_qkv<<<768, 512, 0, stream>>>(xbf, wtq, wtv, bq, bk, bv, qb, kbuf, vbuf, QSCALE);
  k_attn<<<512, 512, 0, stream>>>(qb, kbuf, vbuf, ctx);
  k_oproj<<<512, 256, 0, stream>>>(ctx, wto, bo, x, out);
  k_ln<<<2048, 256, 0, stream>>>(out, gamma, beta);
}

// Round 18
// 204.326 us; speedup vs baseline: 1.0270x; 1.0270x over previous
//
#include <hip/hip_runtime.h>
#include <hip/hip_bf16.h>
#include <stdint.h>

typedef short sh4 __attribute__((ext_vector_type(4)));
typedef short sh8 __attribute__((ext_vector_type(8)));
typedef float fl4 __attribute__((ext_vector_type(4)));
typedef float f32x4 __attribute__((ext_vector_type(4)));
typedef float f32x16 __attribute__((ext_vector_type(16)));
typedef uint32_t u32x4 __attribute__((ext_vector_type(4)));

static __device__ __forceinline__ short f2bf(float f) {
  union { float f; uint32_t u; } v;
  v.f = f;
  uint32_t r = v.u + 0x7fffu + ((v.u >> 16) & 1u);
  return (short)(r >> 16);
}

static __device__ __forceinline__ uint32_t cvt_pk_bf16(float a, float b) {
  uint32_t r;
  asm("v_cvt_pk_bf16_f32 %0, %1, %2" : "=v"(r) : "v"(a), "v"(b));
  return r;
}

static __device__ __forceinline__ void pl32swap(uint32_t& a, uint32_t& b) {
  asm volatile("v_permlane32_swap_b32 %0, %1" : "+v"(a), "+v"(b));
}

static __device__ __forceinline__ void gload_lds16(const void* g, void* l) {
  __builtin_amdgcn_global_load_lds((const __attribute__((address_space(1))) void*)g,
                                   (__attribute__((address_space(3))) void*)l, 16, 0, 0);
}

// ---------- weight transpose + convert (z<4): T[n][k] = bf16(W[k][n]); z==4: x -> bf16 ----------
__global__ __launch_bounds__(256) void k_wt(const float* __restrict__ Wq, const float* __restrict__ Wk,
                                            const float* __restrict__ Wv, const float* __restrict__ Wo,
                                            short* __restrict__ Tq, short* __restrict__ Tk,
                                            short* __restrict__ Tv, short* __restrict__ To,
                                            const float* __restrict__ x, short* __restrict__ xbf) {
  if (blockIdx.z == 4) {
    int tid = threadIdx.y * 32 + threadIdx.x;
    size_t base = ((size_t)blockIdx.y * 32 + blockIdx.x) * 8192;
#pragma unroll
    for (int i = 0; i < 8; i++) {
      size_t idx = base + (size_t)i * 1024 + tid * 4;
      fl4 v = *(const fl4*)&x[idx];
      sh4 r;
#pragma unroll
      for (int j = 0; j < 4; j++) r[j] = f2bf(v[j]);
      *(sh4*)&xbf[idx] = r;
    }
    return;
  }
  const float* W = blockIdx.z == 0 ? Wq : blockIdx.z == 1 ? Wk : blockIdx.z == 2 ? Wv : Wo;
  short* T = blockIdx.z == 0 ? Tq : blockIdx.z == 1 ? Tk : blockIdx.z == 2 ? Tv : To;
  __shared__ float tile[32][33];
  int n0 = blockIdx.x * 32, k0 = blockIdx.y * 32;
  int tx = threadIdx.x, ty = threadIdx.y;
#pragma unroll
  for (int p = 0; p < 4; p++) tile[ty + 8 * p][tx] = W[(size_t)(k0 + ty + 8 * p) * 1024 + n0 + tx];
  __syncthreads();
#pragma unroll
  for (int p = 0; p < 4; p++) T[(size_t)(n0 + ty + 8 * p) * 1024 + k0 + tx] = f2bf(tile[tx][ty + 8 * p]);
}

// ======== counted-vmcnt 3-buffer pipeline; VM = per-wave loads per tile (string literal) ========
#define PIPE_LOOP(STAGE_BODY, COMPUTE_BODY, VM)                          \
  STAGE_BODY(0, 0);                                                      \
  STAGE_BODY(1, 1);                                                      \
  {                                                                      \
    int bufc = 0, bufs = 2;                                              \
    for (int it = 0; it < 32; it++) {                                    \
      if (it < 31)                                                       \
        asm volatile("s_waitcnt vmcnt(" VM ")" ::: "memory");            \
      else                                                               \
        asm volatile("s_waitcnt vmcnt(0)" ::: "memory");                 \
      __builtin_amdgcn_s_barrier();                                      \
      if (it + 2 < 32) { STAGE_BODY(it + 2, bufs); }                     \
      __builtin_amdgcn_sched_barrier(0);                                 \
      { int buf = bufc; COMPUTE_BODY }                                   \
      bufc = bufc == 2 ? 0 : bufc + 1;                                   \
      bufs = bufs == 2 ? 0 : bufs + 1;                                   \
      asm volatile("" ::: "memory");                                     \
    }                                                                    \
  }

// ---------- Q/K projection GEMM: 256x128 tile, 512 threads, row-major coalesced staging ----------
__global__ __launch_bounds__(512, 4) void k_qk(const short* __restrict__ A, const short* __restrict__ WT2,
                                               const float* __restrict__ bq, const float* __restrict__ bk,
                                               short* __restrict__ Qo, short* __restrict__ Ko, float qscale) {
  __shared__ __align__(16) short As[3][256 * 32];  // 48KB
  __shared__ __align__(16) short Bs[3][128 * 32];  // 24KB
  const int xcd = blockIdx.x & 7, j = blockIdx.x >> 3;
  const int m0 = (j >> 1) * 256, n0 = (xcd * 2 + (j & 1)) * 128;
  const int sec = n0 >> 10;  // 0=Q 1=K
  const float* bias = sec == 0 ? bq : bk;
  short* Out = sec == 0 ? Qo : Ko;
  const float scale = sec == 0 ? qscale : 1.f;
  const int t = threadIdx.x;
  const int lane = t & 63, w = t >> 6;
  const int wr = w >> 1, wc = w & 1;
  const int l15 = lane & 15, g = lane >> 4;
  f32x4 acc[4][4];
#pragma unroll
  for (int mi = 0; mi < 4; mi++)
#pragma unroll
    for (int ni = 0; ni < 4; ni++) acc[mi][ni] = (f32x4){0.f, 0.f, 0.f, 0.f};

#define QK_STAGE(kt, buf)                                                                     \
  {                                                                                           \
    int r0 = w * 32;                                                                          \
    _Pragma("unroll") for (int i = 0; i < 2; i++) {                                           \
      int row = r0 + i * 16 + (lane >> 2);                                                    \
      gload_lds16(&A[(size_t)(m0 + row) * 1024 + (kt) * 32 + (lane & 3) * 8],                 \
                  &As[buf][(r0 + i * 16) * 32]);                                              \
    }                                                                                         \
    int brow = w * 16 + (lane >> 2);                                                          \
    gload_lds16(&WT2[(size_t)(n0 + brow) * 1024 + (kt) * 32 + (lane & 3) * 8],                \
                &Bs[buf][(w * 16) * 32]);                                                     \
  }

#define QK_COMPUTE                                                                            \
  sh8 a[4], b[4];                                                                             \
  _Pragma("unroll") for (int i = 0; i < 4; i++)                                               \
      a[i] = *(sh8*)&As[buf][(wr * 64 + i * 16 + l15) * 32 + g * 8];                          \
  _Pragma("unroll") for (int i = 0; i < 4; i++)                                               \
      b[i] = *(sh8*)&Bs[buf][(wc * 64 + i * 16 + l15) * 32 + g * 8];                          \
  _Pragma("unroll") for (int mi = 0; mi < 4; mi++)                                            \
      _Pragma("unroll") for (int ni = 0; ni < 4; ni++)                                        \
          acc[mi][ni] = __builtin_amdgcn_mfma_f32_16x16x32_bf16(b[ni], a[mi], acc[mi][ni], 0, 0, 0);

  PIPE_LOOP(QK_STAGE, QK_COMPUTE, "3")

#pragma unroll
  for (int ni = 0; ni < 4; ni++) {
    int nbase = n0 + wc * 64 + ni * 16 + g * 4;
    int nn0 = nbase & 1023;
    fl4 bv4 = *(const fl4*)&bias[nn0];
    int h = nn0 >> 6, dh0 = nn0 & 63;
#pragma unroll
    for (int mi = 0; mi < 4; mi++) {
      int m = m0 + wr * 64 + mi * 16 + l15;
      int bb = m >> 11, s = m & 2047;
      uint2 dd;
      dd.x = cvt_pk_bf16((acc[mi][ni][0] + bv4[0]) * scale, (acc[mi][ni][1] + bv4[1]) * scale);
      dd.y = cvt_pk_bf16((acc[mi][ni][2] + bv4[2]) * scale, (acc[mi][ni][3] + bv4[3]) * scale);
      *(uint2*)&Out[(((size_t)bb * 16 + h) * 2048 + s) * 64 + dh0] = dd;
    }
  }
}

// ---------- V projection GEMM: 128x128, 16x16, coalesced staging ----------
__global__ __launch_bounds__(256) void k_v(const short* __restrict__ A, const short* __restrict__ WTv,
                                           const float* __restrict__ bv, short* __restrict__ Vo) {
  __shared__ __align__(16) short As[3][128 * 32];
  __shared__ __align__(16) short Bs[3][128 * 32];
  const int xcd = blockIdx.x & 7, j = blockIdx.x >> 3;
  const int m0 = (xcd + 8 * (j & 7)) * 128, n0 = (j >> 3) * 128;
  const int t = threadIdx.x;
  const int lane = t & 63, w = t >> 6;
  const int wr = w >> 1, wc = w & 1;
  const int l15 = lane & 15, g = lane >> 4;
  f32x4 acc[4][4];
#pragma unroll
  for (int mi = 0; mi < 4; mi++)
#pragma unroll
    for (int ni = 0; ni < 4; ni++) acc[mi][ni] = (f32x4){0.f, 0.f, 0.f, 0.f};

#define V_STAGE(kt, buf)                                                                      \
  {                                                                                           \
    int r0 = w * 32;                                                                          \
    _Pragma("unroll") for (int i = 0; i < 2; i++) {                                           \
      int row = r0 + i * 16 + (lane >> 2);                                                    \
      gload_lds16(&A[(size_t)(m0 + row) * 1024 + (kt) * 32 + (lane & 3) * 8],                 \
                  &As[buf][(r0 + i * 16) * 32]);                                              \
      gload_lds16(&WTv[(size_t)(n0 + row) * 1024 + (kt) * 32 + (lane & 3) * 8],               \
                  &Bs[buf][(r0 + i * 16) * 32]);                                              \
    }                                                                                         \
  }

#define V_COMPUTE                                                                             \
  sh8 a[4], b[4];                                                                             \
  _Pragma("unroll") for (int i = 0; i < 4; i++)                                               \
      a[i] = *(sh8*)&As[buf][(wr * 64 + i * 16 + l15) * 32 + g * 8];                          \
  _Pragma("unroll") for (int i = 0; i < 4; i++)                                               \
      b[i] = *(sh8*)&Bs[buf][(wc * 64 + i * 16 + l15) * 32 + g * 8];                          \
  _Pragma("unroll") for (int mi = 0; mi < 4; mi++)                                            \
      _Pragma("unroll") for (int ni = 0; ni < 4; ni++)                                        \
          acc[mi][ni] = __builtin_amdgcn_mfma_f32_16x16x32_bf16(a[mi], b[ni], acc[mi][ni], 0, 0, 0);

  PIPE_LOOP(V_STAGE, V_COMPUTE, "4")

#pragma unroll
  for (int ni = 0; ni < 4; ni++) {
    int col = n0 + wc * 64 + ni * 16 + l15;
    int nn = col & 1023;
    float bvv = bv[nn];
    int h = nn >> 6, dh = nn & 63;
#pragma unroll
    for (int mi = 0; mi < 4; mi++) {
      int mr = m0 + wr * 64 + mi * 16 + g * 4;
      int bb = mr >> 11, s = mr & 2047;
      uint2 dd;
      dd.x = cvt_pk_bf16(acc[mi][ni][0] + bvv, acc[mi][ni][1] + bvv);
      dd.y = cvt_pk_bf16(acc[mi][ni][2] + bvv, acc[mi][ni][3] + bvv);
      *(uint2*)&Vo[(((size_t)bb * 16 + h) * 64 + dh) * 2048 + s] = dd;
    }
  }
}

// ---------- output projection GEMM + bias + residual ----------
__global__ __launch_bounds__(256) void k_oproj(const short* __restrict__ A, const short* __restrict__ BT,
                                               const float* __restrict__ bias, const float* __restrict__ X,
                                               float* __restrict__ Out) {
  __shared__ __align__(16) short As[3][128 * 32];
  __shared__ __align__(16) short Bs[3][128 * 32];
  const int xcd = blockIdx.x & 7, j = blockIdx.x >> 3;
  const int m0 = (xcd + 8 * (j & 7)) * 128, n0 = (j >> 3) * 128;
  const int t = threadIdx.x;
  const int lane = t & 63, w = t >> 6;
  const int wr = w >> 1, wc = w & 1;
  const int l15 = lane & 15, g = lane >> 4;
  f32x4 acc[4][4];
#pragma unroll
  for (int mi = 0; mi < 4; mi++)
#pragma unroll
    for (int ni = 0; ni < 4; ni++) acc[mi][ni] = (f32x4){0.f, 0.f, 0.f, 0.f};

#define O_STAGE(kt, buf)                                                                      \
  {                                                                                           \
    int r0 = w * 32;                                                                          \
    _Pragma("unroll") for (int i = 0; i < 2; i++) {                                           \
      int row = r0 + i * 16 + (lane >> 2);                                                    \
      gload_lds16(&A[(size_t)(m0 + row) * 1024 + (kt) * 32 + (lane & 3) * 8],                 \
                  &As[buf][(r0 + i * 16) * 32]);                                              \
      gload_lds16(&BT[(size_t)(n0 + row) * 1024 + (kt) * 32 + (lane & 3) * 8],                \
                  &Bs[buf][(r0 + i * 16) * 32]);                                              \
    }                                                                                         \
  }

#define O_COMPUTE                                                                             \
  sh8 a[4], b[4];                                                                             \
  _Pragma("unroll") for (int i = 0; i < 4; i++)                                               \
      a[i] = *(sh8*)&As[buf][(wr * 64 + i * 16 + l15) * 32 + g * 8];                          \
  _Pragma("unroll") for (int i = 0; i < 4; i++)                                               \
      b[i] = *(sh8*)&Bs[buf][(wc * 64 + i * 16 + l15) * 32 + g * 8];                          \
  _Pragma("unroll") for (int mi = 0; mi < 4; mi++)                                            \
      _Pragma("unroll") for (int ni = 0; ni < 4; ni++)                                        \
          acc[mi][ni] = __builtin_amdgcn_mfma_f32_16x16x32_bf16(b[ni], a[mi], acc[mi][ni], 0, 0, 0);

  PIPE_LOOP(O_STAGE, O_COMPUTE, "4")

#pragma unroll
  for (int ni = 0; ni < 4; ni++) {
    int nbase = n0 + wc * 64 + ni * 16 + g * 4;
    fl4 bv4 = *(const fl4*)&bias[nbase];
#pragma unroll
    for (int mi = 0; mi < 4; mi++) {
      int m = m0 + wr * 64 + mi * 16 + l15;
      fl4 xv = *(const fl4*)&X[(size_t)m * 1024 + nbase];
      fl4 r;
#pragma unroll
      for (int e = 0; e < 4; e++) r[e] = acc[mi][ni][e] + bv4[e] + xv[e];
      *(fl4*)&Out[(size_t)m * 1024 + nbase] = r;
    }
  }
}

// ---------- flash attention v9 (best known): cross-tile pipelined, frag-order LDS ----------
__global__ __launch_bounds__(512, 4) void k_attn(const short* __restrict__ Q, const short* __restrict__ K,
                                                 const short* __restrict__ Vt, short* __restrict__ CTX) {
  const int nid = (blockIdx.x & 7) * 64 + (blockIdx.x >> 3);
  const int qbi = nid & 7, h = (nid >> 3) & 15, b = nid >> 7;
  const int q0 = qbi * 256;
  const size_t ho = (((size_t)b * 16 + h) * 2048) * 64;
  const short* Qh = Q + ho;
  const short* Kh = K + ho;
  const short* Vh = Vt + ho;
  __shared__ __align__(16) short Ks[3][8 * 512];  // 24KB
  __shared__ __align__(16) short Vs[4][8 * 512];  // 32KB
  const int t = threadIdx.x, lane = t & 63, w = t >> 6;  // w in [0,8)
  const int l31 = lane & 31, hi = lane >> 5;

  sh8 qreg[4];
#pragma unroll
  for (int ks = 0; ks < 4; ks++)
    qreg[ks] = *(const sh8*)&Qh[(size_t)(q0 + w * 32 + l31) * 64 + ks * 16 + hi * 8];

  f32x16 zinit;
#pragma unroll
  for (int r = 0; r < 16; r++) zinit[r] = 0.f;

  f32x16 oc0 = zinit, oc1 = zinit;
  float l_s = 0.f;
  u32x4 pwp[4];  // packed P of previous tile

  auto stageK = [&](int kt, int buf) {
    gload_lds16(&Kh[(size_t)(kt * 64 + (w >> 2) * 32 + l31) * 64 + (w & 3) * 16 + hi * 8],
                (char*)&Ks[buf][0] + w * 1024);
  };
  auto stageV = [&](int kt, int buf) {
    gload_lds16(&Vh[(size_t)((w >> 2) * 32 + l31) * 2048 + kt * 64 + (w & 3) * 16 + hi * 8],
                (char*)&Vs[buf][0] + w * 1024);
  };

  stageK(0, 0); stageV(0, 0);
  stageK(1, 1); stageV(1, 1);

  for (int kt = 0; kt < 32; kt++) {
    if (kt < 31)
      asm volatile("s_waitcnt vmcnt(2)" ::: "memory");
    else
      asm volatile("s_waitcnt vmcnt(0)" ::: "memory");
    __builtin_amdgcn_s_barrier();
    if (kt + 2 < 32) { stageK(kt + 2, (kt + 2) % 3); stageV(kt + 2, (kt + 2) & 3); }
    __builtin_amdgcn_sched_barrier(0);
    const int kbuf = kt % 3;

    // ---- QK(t): issue first so results cook while PV(t-1) runs ----
    f32x16 s0, s1;
    __builtin_amdgcn_s_setprio(1);
#pragma unroll
    for (int ks = 0; ks < 4; ks++) {
      sh8 ak0 = *(sh8*)((char*)&Ks[kbuf][0] + ks * 1024 + lane * 16);
      sh8 ak1 = *(sh8*)((char*)&Ks[kbuf][0] + (4 + ks) * 1024 + lane * 16);
      if (ks == 0) {
        s0 = __builtin_amdgcn_mfma_f32_32x32x16_bf16(ak0, qreg[0], zinit, 0, 0, 0);
        s1 = __builtin_amdgcn_mfma_f32_32x32x16_bf16(ak1, qreg[0], zinit, 0, 0, 0);
      } else {
        s0 = __builtin_amdgcn_mfma_f32_32x32x16_bf16(ak0, qreg[ks], s0, 0, 0, 0);
        s1 = __builtin_amdgcn_mfma_f32_32x32x16_bf16(ak1, qreg[ks], s1, 0, 0, 0);
      }
    }

    // ---- PV(t-1): independent MFMA work filling the QK latency gap ----
    if (kt > 0) {
      const int vb = (kt - 1) & 3;
#pragma unroll
      for (int ks = 0; ks < 4; ks++) {
        sh8 pb = __builtin_bit_cast(sh8, pwp[ks]);
        sh8 av0 = *(sh8*)((char*)&Vs[vb][0] + ks * 1024 + lane * 16);
        sh8 av1 = *(sh8*)((char*)&Vs[vb][0] + (4 + ks) * 1024 + lane * 16);
        oc0 = __builtin_amdgcn_mfma_f32_32x32x16_bf16(av0, pb, oc0, 0, 0, 0);
        oc1 = __builtin_amdgcn_mfma_f32_32x32x16_bf16(av1, pb, oc1, 0, 0, 0);
      }
    }
    __builtin_amdgcn_s_setprio(0);

    // ---- softmax numerator p = exp2(s); accumulate denominator ----
    float ps = 0.f;
#pragma unroll
    for (int r = 0; r < 16; r++) { s0[r] = __builtin_amdgcn_exp2f(s0[r]); ps += s0[r]; }
#pragma unroll
    for (int r = 0; r < 16; r++) { s1[r] = __builtin_amdgcn_exp2f(s1[r]); ps += s1[r]; }
    l_s += ps;

    // ---- pack P -> pwp (cvt_pk + permlane32_swap), used by NEXT iteration's PV ----
    {
      uint32_t a0 = cvt_pk_bf16(s0[0], s0[1]), a1 = cvt_pk_bf16(s0[2], s0[3]);
      uint32_t b0 = cvt_pk_bf16(s0[4], s0[5]), b1 = cvt_pk_bf16(s0[6], s0[7]);
      uint32_t c0 = cvt_pk_bf16(s0[8], s0[9]), c1 = cvt_pk_bf16(s0[10], s0[11]);
      uint32_t d0 = cvt_pk_bf16(s0[12], s0[13]), d1 = cvt_pk_bf16(s0[14], s0[15]);
      pl32swap(a0, b0); pl32swap(a1, b1); pl32swap(c0, d0); pl32swap(c1, d1);
      pwp[0] = (u32x4){a0, a1, b0, b1};
      pwp[1] = (u32x4){c0, c1, d0, d1};
      a0 = cvt_pk_bf16(s1[0], s1[1]); a1 = cvt_pk_bf16(s1[2], s1[3]);
      b0 = cvt_pk_bf16(s1[4], s1[5]); b1 = cvt_pk_bf16(s1[6], s1[7]);
      c0 = cvt_pk_bf16(s1[8], s1[9]); c1 = cvt_pk_bf16(s1[10], s1[11]);
      d0 = cvt_pk_bf16(s1[12], s1[13]); d1 = cvt_pk_bf16(s1[14], s1[15]);
      pl32swap(a0, b0); pl32swap(a1, b1); pl32swap(c0, d0); pl32swap(c1, d1);
      pwp[2] = (u32x4){a0, a1, b0, b1};
      pwp[3] = (u32x4){c0, c1, d0, d1};
    }
    asm volatile("" ::: "memory");
  }

  // ---- tail: PV(31) ----
  {
    const int vb = 31 & 3;
    __builtin_amdgcn_s_setprio(1);
#pragma unroll
    for (int ks = 0; ks < 4; ks++) {
      sh8 pb = __builtin_bit_cast(sh8, pwp[ks]);
      sh8 av0 = *(sh8*)((char*)&Vs[vb][0] + ks * 1024 + lane * 16);
      sh8 av1 = *(sh8*)((char*)&Vs[vb][0] + (4 + ks) * 1024 + lane * 16);
      oc0 = __builtin_amdgcn_mfma_f32_32x32x16_bf16(av0, pb, oc0, 0, 0, 0);
      oc1 = __builtin_amdgcn_mfma_f32_32x32x16_bf16(av1, pb, oc1, 0, 0, 0);
    }
    __builtin_amdgcn_s_setprio(0);
  }

  l_s += __shfl_xor(l_s, 32);
  float li = 1.f / l_s;
  int s = q0 + w * 32 + l31;
  size_t obase = (((size_t)b * 2048 + s) * 16 + h) * 64;
#pragma unroll
  for (int rq = 0; rq < 4; rq++) {
    uint2 dd;
    dd.x = cvt_pk_bf16(oc0[4 * rq] * li, oc0[4 * rq + 1] * li);
    dd.y = cvt_pk_bf16(oc0[4 * rq + 2] * li, oc0[4 * rq + 3] * li);
    *(uint2*)&CTX[obase + rq * 8 + hi * 4] = dd;
    dd.x = cvt_pk_bf16(oc1[4 * rq] * li, oc1[4 * rq + 1] * li);
    dd.y = cvt_pk_bf16(oc1[4 * rq + 2] * li, oc1[4 * rq + 3] * li);
    *(uint2*)&CTX[obase + 32 + rq * 8 + hi * 4] = dd;
  }
}

// ---------- in-place LayerNorm over d_out rows ----------
__global__ __launch_bounds__(256) void k_ln(float* __restrict__ Out, const float* __restrict__ gamma,
                                            const float* __restrict__ beta) {
  int row = blockIdx.x * 4 + (threadIdx.x >> 6);
  int lane = threadIdx.x & 63;
  float* p = Out + (size_t)row * 1024;
  fl4 v[4];
  float s = 0.f, s2 = 0.f;
#pragma unroll
  for (int j = 0; j < 4; j++) {
    v[j] = *(fl4*)&p[lane * 4 + j * 256];
#pragma unroll
    for (int e = 0; e < 4; e++) { s += v[j][e]; s2 += v[j][e] * v[j][e]; }
  }
#pragma unroll
  for (int off = 1; off < 64; off <<= 1) {
    s += __shfl_xor(s, off);
    s2 += __shfl_xor(s2, off);
  }
  float mu = s * (1.f / 1024.f);
  float var = s2 * (1.f / 1024.f) - mu * mu;
  float inv = rsqrtf(var + 1e-5f);
#pragma unroll
  for (int j = 0; j < 4; j++) {
    fl4 r;
#pragma unroll
    for (int e = 0; e < 4; e++) {
      int c = lane * 4 + j * 256 + e;
      r[e] = (v[j][e] - mu) * inv * gamma[c] + beta[c];
    }
    *(fl4*)&p[lane * 4 + j * 256] = r;
  }
}

extern "C" void kernel_launch(void* const* d_in, const int* in_sizes, int n_in,
                              void* d_out, int out_size, void* d_ws, size_t ws_size,
                              hipStream_t stream) {
  (void)in_sizes; (void)n_in; (void)out_size; (void)ws_size;
  const float* x = (const float*)d_in[0];
  const float* Wq = (const float*)d_in[1];
  const float* bq = (const float*)d_in[2];
  const float* Wk = (const float*)d_in[3];
  const float* bk = (const float*)d_in[4];
  const float* Wv = (const float*)d_in[5];
  const float* bv = (const float*)d_in[6];
  const float* Wo = (const float*)d_in[7];
  const float* bo = (const float*)d_in[8];
  const float* gamma = (const float*)d_in[9];
  const float* beta = (const float*)d_in[10];
  float* out = (float*)d_out;
  char* ws = (char*)d_ws;
  short* xbf = (short*)(ws);
  short* wtq = (short*)(ws + (16ull << 20));  // wtq/wtk contiguous => WT2[2048][1024]
  short* wtk = (short*)(ws + (18ull << 20));
  short* wtv = (short*)(ws + (20ull << 20));
  short* wto = (short*)(ws + (22ull << 20));
  short* qb  = (short*)(ws + (24ull << 20));
  short* kbuf = (short*)(ws + (40ull << 20));
  short* vbuf = (short*)(ws + (56ull << 20));
  short* ctx = (short*)(ws + (72ull << 20));

  const float QSCALE = 0.125f * 1.44269504088896f;  // 1/sqrt(Dh) * log2(e)

  k_wt<<<dim3(32, 32, 5), dim3(32, 8), 0, stream>>>(Wq, Wk, Wv, Wo, wtq, wtk, wtv, wto, x, xbf);
  k_qk<<<512, 512, 0, stream>>>(xbf, wtq, bq, bk, qb, kbuf, QSCALE);
  k_v<<<512, 256, 0, stream>>>(xbf, wtv, bv, vbuf);
  k_attn<<<512, 512, 0, stream>>>(qb, kbuf, vbuf, ctx);
  k_oproj<<<512, 256, 0, stream>>>(ctx, wto, bo, x, out);
  k_ln<<<2048, 256, 0, stream>>>(out, gamma, beta);
}